// Round 10
// baseline (1223.193 us; speedup 1.0000x reference)
//
#include <hip/hip_runtime.h>

#define NN 100000
#define NE 600000
#define HH 128
#define NL 5
#define BN_EPS 1e-5f
#define NB 391   // (NN+255)/256
#define NBS 782  // (NN+127)/128  bnstats blocks

typedef float f4 __attribute__((ext_vector_type(4)));
typedef float f2 __attribute__((ext_vector_type(2)));
typedef _Float16 h8 __attribute__((ext_vector_type(8)));
typedef _Float16 h2x __attribute__((ext_vector_type(2)));

// ---------------- edge-index dtype probe + normalize to int32 ----------------
__global__ void k_probe(const unsigned long long* __restrict__ e, int* __restrict__ flag) {
    if (blockIdx.x == 0 && threadIdx.x == 0) {
        int ok = 1;
        for (int i = 0; i < 64; ++i)
            if (e[i] >= (unsigned long long)NN) ok = 0;
        *flag = ok; // 1 => int64, 0 => int32
    }
}

__global__ void k_convert(const void* __restrict__ src, const int* __restrict__ flag,
                          int* __restrict__ dst) {
    int i = blockIdx.x * 256 + threadIdx.x;
    if (i >= 2 * NE) return;
    if (*flag) dst[i] = (int)((const long long*)src)[i];
    else       dst[i] = ((const int*)src)[i];
}

__global__ void k_zero(int* __restrict__ p, int n) {
    int i = blockIdx.x * 256 + threadIdx.x;
    if (i < n) p[i] = 0;
}

// ---------------- degree / dinv ----------------
__global__ void k_count_deg(const int* __restrict__ col, int* __restrict__ degi) {
    int e = blockIdx.x * 256 + threadIdx.x;
    if (e < NE) atomicAdd(&degi[col[e]], 1);
}

__global__ void k_dinv(const int* __restrict__ degi, float* __restrict__ dinv) {
    int i = blockIdx.x * 256 + threadIdx.x;
    if (i < NN) dinv[i] = rsqrtf((float)degi[i] + 1.0f);
}

// ---------------- prefix scan ----------------
__global__ __launch_bounds__(256) void k_scan1(const int* __restrict__ degi,
                                               int* __restrict__ incl,
                                               int* __restrict__ blocksums) {
    __shared__ int sd[256];
    int tid = threadIdx.x;
    int i = blockIdx.x * 256 + tid;
    int v = (i < NN) ? degi[i] : 0;
    sd[tid] = v;
    __syncthreads();
#pragma unroll
    for (int off = 1; off < 256; off <<= 1) {
        int t = (tid >= off) ? sd[tid - off] : 0;
        __syncthreads();
        sd[tid] += t;
        __syncthreads();
    }
    if (i < NN) incl[i] = sd[tid];
    if (tid == 255) blocksums[blockIdx.x] = sd[255];
}

__global__ __launch_bounds__(512) void k_scan2(const int* __restrict__ blocksums,
                                               int* __restrict__ blockoffs) {
    __shared__ int sd[512];
    int tid = threadIdx.x;
    int v = (tid < NB) ? blocksums[tid] : 0;
    sd[tid] = v;
    __syncthreads();
#pragma unroll
    for (int off = 1; off < 512; off <<= 1) {
        int t = (tid >= off) ? sd[tid - off] : 0;
        __syncthreads();
        sd[tid] += t;
        __syncthreads();
    }
    if (tid < NB) blockoffs[tid] = sd[tid] - v;
}

__global__ void k_scan3(const int* __restrict__ incl, const int* __restrict__ degi,
                        const int* __restrict__ blockoffs,
                        int* __restrict__ offsets, int* __restrict__ cursor) {
    int i = blockIdx.x * 256 + threadIdx.x;
    if (i >= NN) return;
    offsets[i] = incl[i] - degi[i] + blockoffs[blockIdx.x];
    cursor[i] = 0;
}

__global__ void k_scatter(const int* __restrict__ ei, const float* __restrict__ dinv,
                          const int* __restrict__ offsets, int* __restrict__ cursor,
                          int2* __restrict__ csr) {
    int e = blockIdx.x * 256 + threadIdx.x;
    if (e >= NE) return;
    int r = ei[e], c = ei[NE + e];
    int pos = offsets[c] + atomicAdd(&cursor[c], 1);
    int2 v;
    v.x = r;
    v.y = __float_as_int(dinv[r] * dinv[c]);
    csr[pos] = v;
}

// ---- transpose + split-cast weights: Wt{hi,lo}[l][n][k] from W[l][k][n] (fp32) ----
__global__ void k_wt(const float* __restrict__ W, _Float16* __restrict__ Wt_hi,
                     _Float16* __restrict__ Wt_lo) {
    int gid = blockIdx.x * 256 + threadIdx.x; // over NL*128*128
    if (gid >= NL * HH * HH) return;
    int l = gid >> 14;
    int rem = gid & 16383;
    int n = rem >> 7;
    int k = rem & 127;
    float w = W[l * HH * HH + k * HH + n];
    _Float16 hi = (_Float16)w;
    _Float16 lo = (_Float16)(w - (float)hi);
    Wt_hi[gid] = hi;
    Wt_lo[gid] = lo;
}

// ---------------- fused GEMM: h1 = relu?(bn(A)) @ W, split-fp16 MFMA, fp32 I/O ------
// Swapped-operand MFMA: D = W^T·X^T = C^T => f4 C-stores. BN prep fused (LDS).
// h1 = Xhi@Whi + Xhi@Wlo + Xlo@Whi  (error ~2^-22 rel; effectively fp32)
__global__ __launch_bounds__(256) void k_gemm(const float* __restrict__ A,
                                              const _Float16* __restrict__ Wt_hi,
                                              const _Float16* __restrict__ Wt_lo,
                                              const float* __restrict__ stats,
                                              const float* __restrict__ gamma,
                                              const float* __restrict__ beta,
                                              int mode, float negmul,
                                              float* __restrict__ C) {
    __shared__ float s_sc[128], s_sh[128];
    const int tid  = threadIdx.x;
    if (tid < 128) {
        float sc = 1.0f, sh = 0.0f;
        if (mode) {
            const float inv_n = 1.0f / (float)NN;
            float mean = stats[tid] * inv_n;
            float var  = stats[128 + tid] * inv_n - mean * mean;
            sc = gamma[tid] * rsqrtf(var + BN_EPS);
            sh = beta[tid] - mean * sc;
        }
        s_sc[tid] = sc;
        s_sh[tid] = sh;
    }
    __syncthreads();

    const int wave = tid >> 6;
    const int lane = tid & 63;
    const int r    = lane & 15;
    const int kg   = lane >> 4;        // 0..3
    const int row0 = blockIdx.x * 128 + wave * 32;

    f4 acc[2][8];
#pragma unroll
    for (int m = 0; m < 2; ++m)
#pragma unroll
        for (int n = 0; n < 8; ++n) acc[m][n] = (f4)0.0f;

    int ra0 = row0 + r;       if (ra0 >= NN) ra0 = NN - 1;
    int ra1 = row0 + 16 + r;  if (ra1 >= NN) ra1 = NN - 1;
    const float* A0 = A + (size_t)ra0 * HH + kg * 8;
    const float* A1 = A + (size_t)ra1 * HH + kg * 8;
    const _Float16* BpH = Wt_hi + (size_t)r * HH + kg * 8;  // + n*16*HH + kc*32
    const _Float16* BpL = Wt_lo + (size_t)r * HH + kg * 8;

#pragma unroll
    for (int kc = 0; kc < 4; ++kc) {
        const int k0 = kc * 32 + kg * 8;
        f4 scA = *reinterpret_cast<const f4*>(&s_sc[k0]);
        f4 scB = *reinterpret_cast<const f4*>(&s_sc[k0 + 4]);
        f4 shA = *reinterpret_cast<const f4*>(&s_sh[k0]);
        f4 shB = *reinterpret_cast<const f4*>(&s_sh[k0 + 4]);
        f4 a0x = *reinterpret_cast<const f4*>(A0 + kc * 32);
        f4 a0y = *reinterpret_cast<const f4*>(A0 + kc * 32 + 4);
        f4 a1x = *reinterpret_cast<const f4*>(A1 + kc * 32);
        f4 a1y = *reinterpret_cast<const f4*>(A1 + kc * 32 + 4);
        h8 a0hi, a0lo, a1hi, a1lo;
#pragma unroll
        for (int j = 0; j < 4; ++j) {
            float t;
            t = fmaf(a0x[j], scA[j], shA[j]); t = fmaxf(t, t * negmul);
            a0hi[j] = (_Float16)t;      a0lo[j] = (_Float16)(t - (float)a0hi[j]);
            t = fmaf(a0y[j], scB[j], shB[j]); t = fmaxf(t, t * negmul);
            a0hi[j + 4] = (_Float16)t;  a0lo[j + 4] = (_Float16)(t - (float)a0hi[j + 4]);
            t = fmaf(a1x[j], scA[j], shA[j]); t = fmaxf(t, t * negmul);
            a1hi[j] = (_Float16)t;      a1lo[j] = (_Float16)(t - (float)a1hi[j]);
            t = fmaf(a1y[j], scB[j], shB[j]); t = fmaxf(t, t * negmul);
            a1hi[j + 4] = (_Float16)t;  a1lo[j + 4] = (_Float16)(t - (float)a1hi[j + 4]);
        }
#pragma unroll
        for (int n = 0; n < 8; ++n) {
            h8 bh = *reinterpret_cast<const h8*>(BpH + (size_t)n * 16 * HH + kc * 32);
            h8 bl = *reinterpret_cast<const h8*>(BpL + (size_t)n * 16 * HH + kc * 32);
            // D = W^T · X^T : A-operand = weight frag, B-operand = activation frag
            acc[0][n] = __builtin_amdgcn_mfma_f32_16x16x32_f16(bh, a0hi, acc[0][n], 0, 0, 0);
            acc[0][n] = __builtin_amdgcn_mfma_f32_16x16x32_f16(bl, a0hi, acc[0][n], 0, 0, 0);
            acc[0][n] = __builtin_amdgcn_mfma_f32_16x16x32_f16(bh, a0lo, acc[0][n], 0, 0, 0);
            acc[1][n] = __builtin_amdgcn_mfma_f32_16x16x32_f16(bh, a1hi, acc[1][n], 0, 0, 0);
            acc[1][n] = __builtin_amdgcn_mfma_f32_16x16x32_f16(bl, a1hi, acc[1][n], 0, 0, 0);
            acc[1][n] = __builtin_amdgcn_mfma_f32_16x16x32_f16(bh, a1lo, acc[1][n], 0, 0, 0);
        }
    }

    // D^T mapping: lane (r,kg) holds C[row0 + m*16 + r][n*16 + kg*4 + i], i=0..3 -> f4
#pragma unroll
    for (int m = 0; m < 2; ++m) {
        int rr = row0 + m * 16 + r;
        if (rr < NN) {
            float* Crow = C + (size_t)rr * HH + kg * 4;
#pragma unroll
            for (int n = 0; n < 8; ++n)
                *reinterpret_cast<f4*>(Crow + n * 16) = acc[m][n];
        }
    }
}

// ------- gather aggregation (fp32): one wave per node, 4-deep masked unroll -------
__global__ __launch_bounds__(256) void k_gather(const float* __restrict__ h1,
                                                const int* __restrict__ offsets,
                                                const int* __restrict__ degi,
                                                const int2* __restrict__ csr,
                                                const float* __restrict__ dinv,
                                                float* __restrict__ h2) {
    int gid  = blockIdx.x * 256 + threadIdx.x;
    int node = gid >> 6;
    int lane = gid & 63;
    if (node >= NN) return;
    float di = dinv[node];
    f2 acc0 = reinterpret_cast<const f2*>(h1 + (size_t)node * HH)[lane] * (di * di);
    f2 acc1 = (f2)0.0f, acc2 = (f2)0.0f, acc3 = (f2)0.0f;
    const int start = offsets[node];
    const int end   = start + degi[node];
    for (int b = start; b < end; b += 4) {
        int2 ce0 = csr[b];
        int2 ce1 = (b + 1 < end) ? csr[b + 1] : make_int2(0, 0);
        int2 ce2 = (b + 2 < end) ? csr[b + 2] : make_int2(0, 0);
        int2 ce3 = (b + 3 < end) ? csr[b + 3] : make_int2(0, 0);
        f2 v0 = reinterpret_cast<const f2*>(h1 + (size_t)ce0.x * HH)[lane];
        f2 v1 = reinterpret_cast<const f2*>(h1 + (size_t)ce1.x * HH)[lane];
        f2 v2 = reinterpret_cast<const f2*>(h1 + (size_t)ce2.x * HH)[lane];
        f2 v3 = reinterpret_cast<const f2*>(h1 + (size_t)ce3.x * HH)[lane];
        acc0 += v0 * __int_as_float(ce0.y);
        acc1 += v1 * __int_as_float(ce1.y);
        acc2 += v2 * __int_as_float(ce2.y);
        acc3 += v3 * __int_as_float(ce3.y);
    }
    acc0 += acc2;
    acc1 += acc3;
    acc0 += acc1;
    reinterpret_cast<f2*>(h2 + (size_t)node * HH)[lane] = acc0;
}

// ------- BN stats phase 1: per-block partial sum/sumsq, NO atomics -------
// 128 rows/block; partial[block][0..127]=sum, [128..255]=sumsq (f4 stores).
__global__ __launch_bounds__(256) void k_bnstats(const float* __restrict__ h,
                                                 float* __restrict__ partial) {
    __shared__ f4 ls[8][32];
    __shared__ f4 lss[8][32];
    const int q  = threadIdx.x & 31;
    const int rg = threadIdx.x >> 5;
    const int r0 = blockIdx.x * 128;
    int rend = r0 + 128;
    if (rend > NN) rend = NN;
    f4 s = (f4)0.0f, ss = (f4)0.0f;
    for (int r = r0 + rg; r < rend; r += 8) {
        f4 v = *reinterpret_cast<const f4*>(h + (size_t)r * HH + q * 4);
        s += v;
        ss += v * v;
    }
    ls[rg][q] = s;
    lss[rg][q] = ss;
    __syncthreads();
    if (rg == 0) {
        f4 st = ls[0][q];
#pragma unroll
        for (int g = 1; g < 8; ++g) st += ls[g][q];
        *reinterpret_cast<f4*>(&partial[(size_t)blockIdx.x * 256 + q * 4]) = st;
    } else if (rg == 1) {
        f4 sq = lss[0][q];
#pragma unroll
        for (int g = 1; g < 8; ++g) sq += lss[g][q];
        *reinterpret_cast<f4*>(&partial[(size_t)blockIdx.x * 256 + 128 + q * 4]) = sq;
    }
}

// ------- BN stats phase 2: column-reduce the 782 partials (coalesced) -------
__global__ void k_statreduce(const float* __restrict__ partial, float* __restrict__ stats) {
    int c = threadIdx.x; // 256
    float s = 0.0f;
#pragma unroll 4
    for (int b = 0; b < NBS; ++b) s += partial[(size_t)b * 256 + c];
    stats[c] = s;
}

// ------- final-layer BN apply + ReLU (prep fused): fp32 h2 -> fp16 x5 -------
__global__ void k_bnapply(const float* __restrict__ h2, const float* __restrict__ stats,
                          const float* __restrict__ gamma, const float* __restrict__ beta,
                          _Float16* __restrict__ xh) {
    int idx = blockIdx.x * 256 + threadIdx.x; // over NN*64 pairs
    if (idx >= NN * 64) return;
    int cp = idx & 63;
    int c0 = 2 * cp, c1 = c0 + 1;
    const float inv_n = 1.0f / (float)NN;
    float m0 = stats[c0] * inv_n, m1 = stats[c1] * inv_n;
    float v0s = stats[128 + c0] * inv_n - m0 * m0;
    float v1s = stats[128 + c1] * inv_n - m1 * m1;
    float sc0 = gamma[c0] * rsqrtf(v0s + BN_EPS);
    float sc1 = gamma[c1] * rsqrtf(v1s + BN_EPS);
    float sh0 = beta[c0] - m0 * sc0;
    float sh1 = beta[c1] - m1 * sc1;
    f2 v = reinterpret_cast<const f2*>(h2)[idx];
    float t0 = fmaf(v[0], sc0, sh0);
    float t1 = fmaf(v[1], sc1, sh1);
    t0 = fmaxf(t0, 0.0f);
    t1 = fmaxf(t1, 0.0f);
    h2x o;
    o[0] = (_Float16)t0;
    o[1] = (_Float16)t1;
    reinterpret_cast<h2x*>(xh)[idx] = o;
}

// ---------------- final: 16 lanes per edge, fp16 rows, fp32 math ----------------
__global__ __launch_bounds__(256) void k_final(const _Float16* __restrict__ x,
                                               const int* __restrict__ ei,
                                               const float* __restrict__ fcw,
                                               const float* __restrict__ fcb,
                                               float* __restrict__ out) {
    int gid  = blockIdx.x * 256 + threadIdx.x;
    int e    = gid >> 4;          // 16 lanes per edge
    int l16  = gid & 15;
    if (e >= NE) return;
    int a = ei[e];
    int b = ei[NE + e];
    h8 va = *reinterpret_cast<const h8*>(x + (size_t)a * HH + l16 * 8);
    h8 vb = *reinterpret_cast<const h8*>(x + (size_t)b * HH + l16 * 8);
    f4 w0 = *reinterpret_cast<const f4*>(fcw + l16 * 8);
    f4 w1 = *reinterpret_cast<const f4*>(fcw + l16 * 8 + 4);
    float p = 0.0f;
#pragma unroll
    for (int j = 0; j < 4; ++j) {
        p += (float)va[j] * (float)vb[j] * w0[j];
        p += (float)va[j + 4] * (float)vb[j + 4] * w1[j];
    }
#pragma unroll
    for (int off = 8; off > 0; off >>= 1) p += __shfl_xor(p, off, 64);
    if (l16 == 0) out[e] = 1.0f / (1.0f + expf(-(p + fcb[0])));
}

extern "C" void kernel_launch(void* const* d_in, const int* in_sizes, int n_in,
                              void* d_out, int out_size, void* d_ws, size_t ws_size,
                              hipStream_t stream) {
    const float* x   = (const float*)d_in[0];
    const void*  ei_raw = d_in[1];
    const float* cw  = (const float*)d_in[2];
    // d_in[3] = conv_b: cancels exactly through BatchNorm -> unused
    const float* gam = (const float*)d_in[4];
    const float* bet = (const float*)d_in[5];
    const float* fcw = (const float*)d_in[6];
    const float* fcb = (const float*)d_in[7];
    float* out = (float*)d_out;

    const size_t NH = (size_t)NN * HH;
    unsigned char* p = (unsigned char*)d_ws;
    float* h1 = (float*)p;       p += NH * 4;            // fp32 gemm out
    float* h2 = (float*)p;       p += NH * 4;            // fp32 aggregated
    _Float16* xh = (_Float16*)p; p += NH * 2;            // fp16 x5 for edge head
    _Float16* WtH = (_Float16*)p; p += (size_t)NL * HH * HH * 2;
    _Float16* WtL = (_Float16*)p; p += (size_t)NL * HH * HH * 2;
    int2*  csr   = (int2*)p;     p += (size_t)NE * 8;
    float* dinv  = (float*)p;    p += NN * 4;
    float* stats = (float*)p;    p += NL * 256 * 4;
    float* partial = (float*)p;  p += (size_t)NBS * 256 * 4;
    int*   ei    = (int*)p;      p += (size_t)2 * NE * 4;
    int*   degi  = (int*)p;      p += NN * 4;
    int*   incl  = (int*)p;      p += NN * 4;
    int*   offsets = (int*)p;    p += NN * 4;
    int*   cursor  = (int*)p;    p += NN * 4;
    int*   blocksums = (int*)p;  p += NB * 4;
    int*   blockoffs = (int*)p;  p += NB * 4;
    int*   flag  = (int*)p;

    // normalize edge index dtype to int32
    k_probe<<<1, 64, 0, stream>>>((const unsigned long long*)ei_raw, flag);
    k_convert<<<(2 * NE + 255) / 256, 256, 0, stream>>>(ei_raw, flag, ei);

    // degrees -> dinv; CSR build
    k_zero<<<(NN + 255) / 256, 256, 0, stream>>>(degi, NN);
    k_count_deg<<<(NE + 255) / 256, 256, 0, stream>>>(ei + NE, degi);
    k_dinv<<<(NN + 255) / 256, 256, 0, stream>>>(degi, dinv);
    k_scan1<<<NB, 256, 0, stream>>>(degi, incl, blocksums);
    k_scan2<<<1, 512, 0, stream>>>(blocksums, blockoffs);
    k_scan3<<<NB, 256, 0, stream>>>(incl, degi, blockoffs, offsets, cursor);
    k_scatter<<<(NE + 255) / 256, 256, 0, stream>>>(ei, dinv, offsets, cursor, csr);

    // split weights (fp16 hi/lo, transposed)
    k_wt<<<(NL * HH * HH + 255) / 256, 256, 0, stream>>>(cw, WtH, WtL);

    for (int l = 0; l < NL; ++l) {
        k_gemm<<<(NN + 127) / 128, 256, 0, stream>>>(
            (l == 0) ? x : h2, WtH + (size_t)l * HH * HH, WtL + (size_t)l * HH * HH,
            (l == 0) ? stats : stats + (size_t)(l - 1) * 256,
            (l == 0) ? gam : gam + (size_t)(l - 1) * HH,
            (l == 0) ? bet : bet + (size_t)(l - 1) * HH,
            (l == 0) ? 0 : 1, (l == 0) ? 1.0f : 0.0f, h1);
        k_gather<<<(NN * 64 + 255) / 256, 256, 0, stream>>>(h1, offsets, degi, csr, dinv, h2);
        k_bnstats<<<NBS, 256, 0, stream>>>(h2, partial);
        k_statreduce<<<1, 256, 0, stream>>>(partial, stats + (size_t)l * 256);
    }
    // materialize x5 (fp16) for the edge head (BN prep fused)
    k_bnapply<<<(NN * 64 + 255) / 256, 256, 0, stream>>>(h2, stats + (size_t)(NL - 1) * 256,
                                                         gam + (size_t)(NL - 1) * HH,
                                                         bet + (size_t)(NL - 1) * HH, xh);
    k_final<<<(NE * 16 + 255) / 256, 256, 0, stream>>>(xh, ei, fcw, fcb, out);
}

// Round 11
// 776.739 us; speedup vs baseline: 1.5748x; 1.5748x over previous
//
#include <hip/hip_runtime.h>

#define NN 100000
#define NE 600000
#define HH 128
#define NL 5
#define BN_EPS 1e-5f
#define NB 391   // (NN+255)/256
#define NBS 782  // (NN+127)/128  bnstats blocks
#define L2B 32   // level-2 reduce blocks
#define RPB 25   // ceil(NBS/L2B) rows per level-2 block

typedef float f4 __attribute__((ext_vector_type(4)));
typedef float f2 __attribute__((ext_vector_type(2)));
typedef _Float16 h8 __attribute__((ext_vector_type(8)));
typedef _Float16 h2x __attribute__((ext_vector_type(2)));

// ---------------- edge-index dtype probe + normalize to int32 ----------------
__global__ void k_probe(const unsigned long long* __restrict__ e, int* __restrict__ flag) {
    if (blockIdx.x == 0 && threadIdx.x == 0) {
        int ok = 1;
        for (int i = 0; i < 64; ++i)
            if (e[i] >= (unsigned long long)NN) ok = 0;
        *flag = ok; // 1 => int64, 0 => int32
    }
}

__global__ void k_convert(const void* __restrict__ src, const int* __restrict__ flag,
                          int* __restrict__ dst) {
    int i = blockIdx.x * 256 + threadIdx.x;
    if (i >= 2 * NE) return;
    if (*flag) dst[i] = (int)((const long long*)src)[i];
    else       dst[i] = ((const int*)src)[i];
}

__global__ void k_zero(int* __restrict__ p, int n) {
    int i = blockIdx.x * 256 + threadIdx.x;
    if (i < n) p[i] = 0;
}

// ---------------- degree / dinv ----------------
__global__ void k_count_deg(const int* __restrict__ col, int* __restrict__ degi) {
    int e = blockIdx.x * 256 + threadIdx.x;
    if (e < NE) atomicAdd(&degi[col[e]], 1);
}

__global__ void k_dinv(const int* __restrict__ degi, float* __restrict__ dinv) {
    int i = blockIdx.x * 256 + threadIdx.x;
    if (i < NN) dinv[i] = rsqrtf((float)degi[i] + 1.0f);
}

// ---------------- prefix scan ----------------
__global__ __launch_bounds__(256) void k_scan1(const int* __restrict__ degi,
                                               int* __restrict__ incl,
                                               int* __restrict__ blocksums) {
    __shared__ int sd[256];
    int tid = threadIdx.x;
    int i = blockIdx.x * 256 + tid;
    int v = (i < NN) ? degi[i] : 0;
    sd[tid] = v;
    __syncthreads();
#pragma unroll
    for (int off = 1; off < 256; off <<= 1) {
        int t = (tid >= off) ? sd[tid - off] : 0;
        __syncthreads();
        sd[tid] += t;
        __syncthreads();
    }
    if (i < NN) incl[i] = sd[tid];
    if (tid == 255) blocksums[blockIdx.x] = sd[255];
}

__global__ __launch_bounds__(512) void k_scan2(const int* __restrict__ blocksums,
                                               int* __restrict__ blockoffs) {
    __shared__ int sd[512];
    int tid = threadIdx.x;
    int v = (tid < NB) ? blocksums[tid] : 0;
    sd[tid] = v;
    __syncthreads();
#pragma unroll
    for (int off = 1; off < 512; off <<= 1) {
        int t = (tid >= off) ? sd[tid - off] : 0;
        __syncthreads();
        sd[tid] += t;
        __syncthreads();
    }
    if (tid < NB) blockoffs[tid] = sd[tid] - v;
}

__global__ void k_scan3(const int* __restrict__ incl, const int* __restrict__ degi,
                        const int* __restrict__ blockoffs,
                        int* __restrict__ offsets, int* __restrict__ cursor) {
    int i = blockIdx.x * 256 + threadIdx.x;
    if (i >= NN) return;
    offsets[i] = incl[i] - degi[i] + blockoffs[blockIdx.x];
    cursor[i] = 0;
}

__global__ void k_scatter(const int* __restrict__ ei, const float* __restrict__ dinv,
                          const int* __restrict__ offsets, int* __restrict__ cursor,
                          int2* __restrict__ csr) {
    int e = blockIdx.x * 256 + threadIdx.x;
    if (e >= NE) return;
    int r = ei[e], c = ei[NE + e];
    int pos = offsets[c] + atomicAdd(&cursor[c], 1);
    int2 v;
    v.x = r;
    v.y = __float_as_int(dinv[r] * dinv[c]);
    csr[pos] = v;
}

// ---- transpose + split-cast weights: Wt{hi,lo}[l][n][k] from W[l][k][n] (fp32) ----
__global__ void k_wt(const float* __restrict__ W, _Float16* __restrict__ Wt_hi,
                     _Float16* __restrict__ Wt_lo) {
    int gid = blockIdx.x * 256 + threadIdx.x; // over NL*128*128
    if (gid >= NL * HH * HH) return;
    int l = gid >> 14;
    int rem = gid & 16383;
    int n = rem >> 7;
    int k = rem & 127;
    float w = W[l * HH * HH + k * HH + n];
    _Float16 hi = (_Float16)w;
    _Float16 lo = (_Float16)(w - (float)hi);
    Wt_hi[gid] = hi;
    Wt_lo[gid] = lo;
}

// ---------------- fused GEMM: h1 = relu?(bn(A)) @ W, split-fp16 MFMA, fp32 I/O ------
// Swapped-operand MFMA: D = W^T·X^T = C^T => f4 C-stores. BN prep fused (LDS).
// h1 = Xhi@Whi + Xhi@Wlo + Xlo@Whi  (error ~2^-22 rel; effectively fp32)
__global__ __launch_bounds__(256) void k_gemm(const float* __restrict__ A,
                                              const _Float16* __restrict__ Wt_hi,
                                              const _Float16* __restrict__ Wt_lo,
                                              const float* __restrict__ stats,
                                              const float* __restrict__ gamma,
                                              const float* __restrict__ beta,
                                              int mode, float negmul,
                                              float* __restrict__ C) {
    __shared__ float s_sc[128], s_sh[128];
    const int tid  = threadIdx.x;
    if (tid < 128) {
        float sc = 1.0f, sh = 0.0f;
        if (mode) {
            const float inv_n = 1.0f / (float)NN;
            float mean = stats[tid] * inv_n;
            float var  = stats[128 + tid] * inv_n - mean * mean;
            sc = gamma[tid] * rsqrtf(var + BN_EPS);
            sh = beta[tid] - mean * sc;
        }
        s_sc[tid] = sc;
        s_sh[tid] = sh;
    }
    __syncthreads();

    const int wave = tid >> 6;
    const int lane = tid & 63;
    const int r    = lane & 15;
    const int kg   = lane >> 4;        // 0..3
    const int row0 = blockIdx.x * 128 + wave * 32;

    f4 acc[2][8];
#pragma unroll
    for (int m = 0; m < 2; ++m)
#pragma unroll
        for (int n = 0; n < 8; ++n) acc[m][n] = (f4)0.0f;

    int ra0 = row0 + r;       if (ra0 >= NN) ra0 = NN - 1;
    int ra1 = row0 + 16 + r;  if (ra1 >= NN) ra1 = NN - 1;
    const float* A0 = A + (size_t)ra0 * HH + kg * 8;
    const float* A1 = A + (size_t)ra1 * HH + kg * 8;
    const _Float16* BpH = Wt_hi + (size_t)r * HH + kg * 8;  // + n*16*HH + kc*32
    const _Float16* BpL = Wt_lo + (size_t)r * HH + kg * 8;

#pragma unroll
    for (int kc = 0; kc < 4; ++kc) {
        const int k0 = kc * 32 + kg * 8;
        f4 scA = *reinterpret_cast<const f4*>(&s_sc[k0]);
        f4 scB = *reinterpret_cast<const f4*>(&s_sc[k0 + 4]);
        f4 shA = *reinterpret_cast<const f4*>(&s_sh[k0]);
        f4 shB = *reinterpret_cast<const f4*>(&s_sh[k0 + 4]);
        f4 a0x = *reinterpret_cast<const f4*>(A0 + kc * 32);
        f4 a0y = *reinterpret_cast<const f4*>(A0 + kc * 32 + 4);
        f4 a1x = *reinterpret_cast<const f4*>(A1 + kc * 32);
        f4 a1y = *reinterpret_cast<const f4*>(A1 + kc * 32 + 4);
        h8 a0hi, a0lo, a1hi, a1lo;
#pragma unroll
        for (int j = 0; j < 4; ++j) {
            float t;
            t = fmaf(a0x[j], scA[j], shA[j]); t = fmaxf(t, t * negmul);
            a0hi[j] = (_Float16)t;      a0lo[j] = (_Float16)(t - (float)a0hi[j]);
            t = fmaf(a0y[j], scB[j], shB[j]); t = fmaxf(t, t * negmul);
            a0hi[j + 4] = (_Float16)t;  a0lo[j + 4] = (_Float16)(t - (float)a0hi[j + 4]);
            t = fmaf(a1x[j], scA[j], shA[j]); t = fmaxf(t, t * negmul);
            a1hi[j] = (_Float16)t;      a1lo[j] = (_Float16)(t - (float)a1hi[j]);
            t = fmaf(a1y[j], scB[j], shB[j]); t = fmaxf(t, t * negmul);
            a1hi[j + 4] = (_Float16)t;  a1lo[j + 4] = (_Float16)(t - (float)a1hi[j + 4]);
        }
#pragma unroll
        for (int n = 0; n < 8; ++n) {
            h8 bh = *reinterpret_cast<const h8*>(BpH + (size_t)n * 16 * HH + kc * 32);
            h8 bl = *reinterpret_cast<const h8*>(BpL + (size_t)n * 16 * HH + kc * 32);
            // D = W^T · X^T : A-operand = weight frag, B-operand = activation frag
            acc[0][n] = __builtin_amdgcn_mfma_f32_16x16x32_f16(bh, a0hi, acc[0][n], 0, 0, 0);
            acc[0][n] = __builtin_amdgcn_mfma_f32_16x16x32_f16(bl, a0hi, acc[0][n], 0, 0, 0);
            acc[0][n] = __builtin_amdgcn_mfma_f32_16x16x32_f16(bh, a0lo, acc[0][n], 0, 0, 0);
            acc[1][n] = __builtin_amdgcn_mfma_f32_16x16x32_f16(bh, a1hi, acc[1][n], 0, 0, 0);
            acc[1][n] = __builtin_amdgcn_mfma_f32_16x16x32_f16(bl, a1hi, acc[1][n], 0, 0, 0);
            acc[1][n] = __builtin_amdgcn_mfma_f32_16x16x32_f16(bh, a1lo, acc[1][n], 0, 0, 0);
        }
    }

    // D^T mapping: lane (r,kg) holds C[row0 + m*16 + r][n*16 + kg*4 + i], i=0..3 -> f4
#pragma unroll
    for (int m = 0; m < 2; ++m) {
        int rr = row0 + m * 16 + r;
        if (rr < NN) {
            float* Crow = C + (size_t)rr * HH + kg * 4;
#pragma unroll
            for (int n = 0; n < 8; ++n)
                *reinterpret_cast<f4*>(Crow + n * 16) = acc[m][n];
        }
    }
}

// ------- gather aggregation (fp32): one wave per node, 4-deep masked unroll -------
__global__ __launch_bounds__(256) void k_gather(const float* __restrict__ h1,
                                                const int* __restrict__ offsets,
                                                const int* __restrict__ degi,
                                                const int2* __restrict__ csr,
                                                const float* __restrict__ dinv,
                                                float* __restrict__ h2) {
    int gid  = blockIdx.x * 256 + threadIdx.x;
    int node = gid >> 6;
    int lane = gid & 63;
    if (node >= NN) return;
    float di = dinv[node];
    f2 acc0 = reinterpret_cast<const f2*>(h1 + (size_t)node * HH)[lane] * (di * di);
    f2 acc1 = (f2)0.0f, acc2 = (f2)0.0f, acc3 = (f2)0.0f;
    const int start = offsets[node];
    const int end   = start + degi[node];
    for (int b = start; b < end; b += 4) {
        int2 ce0 = csr[b];
        int2 ce1 = (b + 1 < end) ? csr[b + 1] : make_int2(0, 0);
        int2 ce2 = (b + 2 < end) ? csr[b + 2] : make_int2(0, 0);
        int2 ce3 = (b + 3 < end) ? csr[b + 3] : make_int2(0, 0);
        f2 v0 = reinterpret_cast<const f2*>(h1 + (size_t)ce0.x * HH)[lane];
        f2 v1 = reinterpret_cast<const f2*>(h1 + (size_t)ce1.x * HH)[lane];
        f2 v2 = reinterpret_cast<const f2*>(h1 + (size_t)ce2.x * HH)[lane];
        f2 v3 = reinterpret_cast<const f2*>(h1 + (size_t)ce3.x * HH)[lane];
        acc0 += v0 * __int_as_float(ce0.y);
        acc1 += v1 * __int_as_float(ce1.y);
        acc2 += v2 * __int_as_float(ce2.y);
        acc3 += v3 * __int_as_float(ce3.y);
    }
    acc0 += acc2;
    acc1 += acc3;
    acc0 += acc1;
    reinterpret_cast<f2*>(h2 + (size_t)node * HH)[lane] = acc0;
}

// ------- BN stats phase 1: per-block partial sum/sumsq, NO atomics -------
// 128 rows/block; partial[block][0..127]=sum, [128..255]=sumsq (f4 stores).
__global__ __launch_bounds__(256) void k_bnstats(const float* __restrict__ h,
                                                 float* __restrict__ partial) {
    __shared__ f4 ls[8][32];
    __shared__ f4 lss[8][32];
    const int q  = threadIdx.x & 31;
    const int rg = threadIdx.x >> 5;
    const int r0 = blockIdx.x * 128;
    int rend = r0 + 128;
    if (rend > NN) rend = NN;
    f4 s = (f4)0.0f, ss = (f4)0.0f;
    for (int r = r0 + rg; r < rend; r += 8) {
        f4 v = *reinterpret_cast<const f4*>(h + (size_t)r * HH + q * 4);
        s += v;
        ss += v * v;
    }
    ls[rg][q] = s;
    lss[rg][q] = ss;
    __syncthreads();
    if (rg == 0) {
        f4 st = ls[0][q];
#pragma unroll
        for (int g = 1; g < 8; ++g) st += ls[g][q];
        *reinterpret_cast<f4*>(&partial[(size_t)blockIdx.x * 256 + q * 4]) = st;
    } else if (rg == 1) {
        f4 sq = lss[0][q];
#pragma unroll
        for (int g = 1; g < 8; ++g) sq += lss[g][q];
        *reinterpret_cast<f4*>(&partial[(size_t)blockIdx.x * 256 + 128 + q * 4]) = sq;
    }
}

// ------- BN stats phase 2a: 32 blocks each sum ~25 partial rows (coalesced) -------
__global__ void k_sred1(const float* __restrict__ partial, float* __restrict__ level2) {
    int c = threadIdx.x; // 256
    int b0 = blockIdx.x * RPB;
    int b1 = b0 + RPB;
    if (b1 > NBS) b1 = NBS;
    float s = 0.0f;
    for (int b = b0; b < b1; ++b) s += partial[(size_t)b * 256 + c];
    level2[(size_t)blockIdx.x * 256 + c] = s;
}

// ------- BN stats phase 2b: final sum over 32 level-2 rows -------
__global__ void k_sred2(const float* __restrict__ level2, float* __restrict__ stats) {
    int c = threadIdx.x; // 256
    float s = 0.0f;
#pragma unroll
    for (int b = 0; b < L2B; ++b) s += level2[(size_t)b * 256 + c];
    stats[c] = s;
}

// ------- final-layer BN apply + ReLU (prep fused): fp32 h2 -> fp16 x5 -------
__global__ void k_bnapply(const float* __restrict__ h2, const float* __restrict__ stats,
                          const float* __restrict__ gamma, const float* __restrict__ beta,
                          _Float16* __restrict__ xh) {
    int idx = blockIdx.x * 256 + threadIdx.x; // over NN*64 pairs
    if (idx >= NN * 64) return;
    int cp = idx & 63;
    int c0 = 2 * cp, c1 = c0 + 1;
    const float inv_n = 1.0f / (float)NN;
    float m0 = stats[c0] * inv_n, m1 = stats[c1] * inv_n;
    float v0s = stats[128 + c0] * inv_n - m0 * m0;
    float v1s = stats[128 + c1] * inv_n - m1 * m1;
    float sc0 = gamma[c0] * rsqrtf(v0s + BN_EPS);
    float sc1 = gamma[c1] * rsqrtf(v1s + BN_EPS);
    float sh0 = beta[c0] - m0 * sc0;
    float sh1 = beta[c1] - m1 * sc1;
    f2 v = reinterpret_cast<const f2*>(h2)[idx];
    float t0 = fmaf(v[0], sc0, sh0);
    float t1 = fmaf(v[1], sc1, sh1);
    t0 = fmaxf(t0, 0.0f);
    t1 = fmaxf(t1, 0.0f);
    h2x o;
    o[0] = (_Float16)t0;
    o[1] = (_Float16)t1;
    reinterpret_cast<h2x*>(xh)[idx] = o;
}

// ---------------- final: 16 lanes per edge, fp16 rows, fp32 math ----------------
__global__ __launch_bounds__(256) void k_final(const _Float16* __restrict__ x,
                                               const int* __restrict__ ei,
                                               const float* __restrict__ fcw,
                                               const float* __restrict__ fcb,
                                               float* __restrict__ out) {
    int gid  = blockIdx.x * 256 + threadIdx.x;
    int e    = gid >> 4;          // 16 lanes per edge
    int l16  = gid & 15;
    if (e >= NE) return;
    int a = ei[e];
    int b = ei[NE + e];
    h8 va = *reinterpret_cast<const h8*>(x + (size_t)a * HH + l16 * 8);
    h8 vb = *reinterpret_cast<const h8*>(x + (size_t)b * HH + l16 * 8);
    f4 w0 = *reinterpret_cast<const f4*>(fcw + l16 * 8);
    f4 w1 = *reinterpret_cast<const f4*>(fcw + l16 * 8 + 4);
    float p = 0.0f;
#pragma unroll
    for (int j = 0; j < 4; ++j) {
        p += (float)va[j] * (float)vb[j] * w0[j];
        p += (float)va[j + 4] * (float)vb[j + 4] * w1[j];
    }
#pragma unroll
    for (int off = 8; off > 0; off >>= 1) p += __shfl_xor(p, off, 64);
    if (l16 == 0) out[e] = 1.0f / (1.0f + expf(-(p + fcb[0])));
}

extern "C" void kernel_launch(void* const* d_in, const int* in_sizes, int n_in,
                              void* d_out, int out_size, void* d_ws, size_t ws_size,
                              hipStream_t stream) {
    const float* x   = (const float*)d_in[0];
    const void*  ei_raw = d_in[1];
    const float* cw  = (const float*)d_in[2];
    // d_in[3] = conv_b: cancels exactly through BatchNorm -> unused
    const float* gam = (const float*)d_in[4];
    const float* bet = (const float*)d_in[5];
    const float* fcw = (const float*)d_in[6];
    const float* fcb = (const float*)d_in[7];
    float* out = (float*)d_out;

    const size_t NH = (size_t)NN * HH;
    unsigned char* p = (unsigned char*)d_ws;
    float* h1 = (float*)p;       p += NH * 4;            // fp32 gemm out
    float* h2 = (float*)p;       p += NH * 4;            // fp32 aggregated
    _Float16* xh = (_Float16*)p; p += NH * 2;            // fp16 x5 for edge head
    _Float16* WtH = (_Float16*)p; p += (size_t)NL * HH * HH * 2;
    _Float16* WtL = (_Float16*)p; p += (size_t)NL * HH * HH * 2;
    int2*  csr   = (int2*)p;     p += (size_t)NE * 8;
    float* dinv  = (float*)p;    p += NN * 4;
    float* stats = (float*)p;    p += NL * 256 * 4;
    float* partial = (float*)p;  p += (size_t)NBS * 256 * 4;
    float* level2  = (float*)p;  p += (size_t)L2B * 256 * 4;
    int*   ei    = (int*)p;      p += (size_t)2 * NE * 4;
    int*   degi  = (int*)p;      p += NN * 4;
    int*   incl  = (int*)p;      p += NN * 4;
    int*   offsets = (int*)p;    p += NN * 4;
    int*   cursor  = (int*)p;    p += NN * 4;
    int*   blocksums = (int*)p;  p += NB * 4;
    int*   blockoffs = (int*)p;  p += NB * 4;
    int*   flag  = (int*)p;

    // normalize edge index dtype to int32
    k_probe<<<1, 64, 0, stream>>>((const unsigned long long*)ei_raw, flag);
    k_convert<<<(2 * NE + 255) / 256, 256, 0, stream>>>(ei_raw, flag, ei);

    // degrees -> dinv; CSR build
    k_zero<<<(NN + 255) / 256, 256, 0, stream>>>(degi, NN);
    k_count_deg<<<(NE + 255) / 256, 256, 0, stream>>>(ei + NE, degi);
    k_dinv<<<(NN + 255) / 256, 256, 0, stream>>>(degi, dinv);
    k_scan1<<<NB, 256, 0, stream>>>(degi, incl, blocksums);
    k_scan2<<<1, 512, 0, stream>>>(blocksums, blockoffs);
    k_scan3<<<NB, 256, 0, stream>>>(incl, degi, blockoffs, offsets, cursor);
    k_scatter<<<(NE + 255) / 256, 256, 0, stream>>>(ei, dinv, offsets, cursor, csr);

    // split weights (fp16 hi/lo, transposed)
    k_wt<<<(NL * HH * HH + 255) / 256, 256, 0, stream>>>(cw, WtH, WtL);

    for (int l = 0; l < NL; ++l) {
        k_gemm<<<(NN + 127) / 128, 256, 0, stream>>>(
            (l == 0) ? x : h2, WtH + (size_t)l * HH * HH, WtL + (size_t)l * HH * HH,
            (l == 0) ? stats : stats + (size_t)(l - 1) * 256,
            (l == 0) ? gam : gam + (size_t)(l - 1) * HH,
            (l == 0) ? bet : bet + (size_t)(l - 1) * HH,
            (l == 0) ? 0 : 1, (l == 0) ? 1.0f : 0.0f, h1);
        k_gather<<<(NN * 64 + 255) / 256, 256, 0, stream>>>(h1, offsets, degi, csr, dinv, h2);
        k_bnstats<<<NBS, 256, 0, stream>>>(h2, partial);
        k_sred1<<<L2B, 256, 0, stream>>>(partial, level2);
        k_sred2<<<1, 256, 0, stream>>>(level2, stats + (size_t)l * 256);
    }
    // materialize x5 (fp16) for the edge head (BN prep fused)
    k_bnapply<<<(NN * 64 + 255) / 256, 256, 0, stream>>>(h2, stats + (size_t)(NL - 1) * 256,
                                                         gam + (size_t)(NL - 1) * HH,
                                                         bet + (size_t)(NL - 1) * HH, xh);
    k_final<<<(NE * 16 + 255) / 256, 256, 0, stream>>>(xh, ei, fcw, fcb, out);
}

// Round 12
// 733.400 us; speedup vs baseline: 1.6678x; 1.0591x over previous
//
#include <hip/hip_runtime.h>

#define NN 100000
#define NE 600000
#define HH 128
#define NL 5
#define BN_EPS 1e-5f
#define NB 391   // (NN+255)/256
#define NBS 782  // (NN+127)/128  bnstats blocks
#define L2B 32   // level-2 reduce blocks
#define RPB 25   // ceil(NBS/L2B) rows per level-2 block

typedef float f4 __attribute__((ext_vector_type(4)));
typedef float f2 __attribute__((ext_vector_type(2)));
typedef _Float16 h8 __attribute__((ext_vector_type(8)));
typedef _Float16 h2x __attribute__((ext_vector_type(2)));

// ---------------- edge-index dtype probe + normalize to int32 ----------------
__global__ void k_probe(const unsigned long long* __restrict__ e, int* __restrict__ flag) {
    if (blockIdx.x == 0 && threadIdx.x == 0) {
        int ok = 1;
        for (int i = 0; i < 64; ++i)
            if (e[i] >= (unsigned long long)NN) ok = 0;
        *flag = ok; // 1 => int64, 0 => int32
    }
}

__global__ void k_convert(const void* __restrict__ src, const int* __restrict__ flag,
                          int* __restrict__ dst) {
    int i = blockIdx.x * 256 + threadIdx.x;
    if (i >= 2 * NE) return;
    if (*flag) dst[i] = (int)((const long long*)src)[i];
    else       dst[i] = ((const int*)src)[i];
}

__global__ void k_zero(int* __restrict__ p, int n) {
    int i = blockIdx.x * 256 + threadIdx.x;
    if (i < n) p[i] = 0;
}

// ---------------- degree / dinv ----------------
__global__ void k_count_deg(const int* __restrict__ col, int* __restrict__ degi) {
    int e = blockIdx.x * 256 + threadIdx.x;
    if (e < NE) atomicAdd(&degi[col[e]], 1);
}

__global__ void k_dinv(const int* __restrict__ degi, float* __restrict__ dinv) {
    int i = blockIdx.x * 256 + threadIdx.x;
    if (i < NN) dinv[i] = rsqrtf((float)degi[i] + 1.0f);
}

// ---------------- prefix scan ----------------
__global__ __launch_bounds__(256) void k_scan1(const int* __restrict__ degi,
                                               int* __restrict__ incl,
                                               int* __restrict__ blocksums) {
    __shared__ int sd[256];
    int tid = threadIdx.x;
    int i = blockIdx.x * 256 + tid;
    int v = (i < NN) ? degi[i] : 0;
    sd[tid] = v;
    __syncthreads();
#pragma unroll
    for (int off = 1; off < 256; off <<= 1) {
        int t = (tid >= off) ? sd[tid - off] : 0;
        __syncthreads();
        sd[tid] += t;
        __syncthreads();
    }
    if (i < NN) incl[i] = sd[tid];
    if (tid == 255) blocksums[blockIdx.x] = sd[255];
}

__global__ __launch_bounds__(512) void k_scan2(const int* __restrict__ blocksums,
                                               int* __restrict__ blockoffs) {
    __shared__ int sd[512];
    int tid = threadIdx.x;
    int v = (tid < NB) ? blocksums[tid] : 0;
    sd[tid] = v;
    __syncthreads();
#pragma unroll
    for (int off = 1; off < 512; off <<= 1) {
        int t = (tid >= off) ? sd[tid - off] : 0;
        __syncthreads();
        sd[tid] += t;
        __syncthreads();
    }
    if (tid < NB) blockoffs[tid] = sd[tid] - v;
}

__global__ void k_scan3(const int* __restrict__ incl, const int* __restrict__ degi,
                        const int* __restrict__ blockoffs,
                        int* __restrict__ offsets, int* __restrict__ cursor) {
    int i = blockIdx.x * 256 + threadIdx.x;
    if (i >= NN) return;
    offsets[i] = incl[i] - degi[i] + blockoffs[blockIdx.x];
    cursor[i] = 0;
}

__global__ void k_scatter(const int* __restrict__ ei, const float* __restrict__ dinv,
                          const int* __restrict__ offsets, int* __restrict__ cursor,
                          int2* __restrict__ csr) {
    int e = blockIdx.x * 256 + threadIdx.x;
    if (e >= NE) return;
    int r = ei[e], c = ei[NE + e];
    int pos = offsets[c] + atomicAdd(&cursor[c], 1);
    int2 v;
    v.x = r;
    v.y = __float_as_int(dinv[r] * dinv[c]);
    csr[pos] = v;
}

// ---- transpose + split-cast weights: Wt{hi,lo}[l][n][k] from W[l][k][n] (fp32) ----
__global__ void k_wt(const float* __restrict__ W, _Float16* __restrict__ Wt_hi,
                     _Float16* __restrict__ Wt_lo) {
    int gid = blockIdx.x * 256 + threadIdx.x; // over NL*128*128
    if (gid >= NL * HH * HH) return;
    int l = gid >> 14;
    int rem = gid & 16383;
    int n = rem >> 7;
    int k = rem & 127;
    float w = W[l * HH * HH + k * HH + n];
    _Float16 hi = (_Float16)w;
    _Float16 lo = (_Float16)(w - (float)hi);
    Wt_hi[gid] = hi;
    Wt_lo[gid] = lo;
}

// ---- per-layer BN scale/shift: sc = gamma*rsqrt(var+eps), sh = beta-mean*sc ----
__global__ void k_prep(const float* __restrict__ stats, const float* __restrict__ gamma,
                       const float* __restrict__ beta, int mode, float* __restrict__ scsh) {
    int k = threadIdx.x; // 128 threads
    float sc = 1.0f, sh = 0.0f;
    if (mode) {
        const float inv_n = 1.0f / (float)NN;
        float mean = stats[k] * inv_n;
        float var  = stats[128 + k] * inv_n - mean * mean;
        sc = gamma[k] * rsqrtf(var + BN_EPS);
        sh = beta[k] - mean * sc;
    }
    scsh[k] = sc;
    scsh[128 + k] = sh;
}

// ---------------- fused GEMM: h1 = relu?(bn(A)) @ W, split-fp16 MFMA, fp32 I/O ------
// B (weights hi+lo) staged ONCE per block into LDS in fragment order: granule
// g = n*256 + kc*64 + kg*16 + r holds Wt[n*16+r][kc*32+kg*8 .. +8]. Inner-loop
// read = lane-sequential ds_read_b128 (canonical conflict-benign pattern).
// Removes the 4x-redundant per-wave global B loads and their L2 latency.
// Swapped-operand MFMA: D = W^T·X^T = C^T => f4 C-stores.
// h1 = Xhi@Whi + Xhi@Wlo + Xlo@Whi  (error ~2^-22 rel; effectively fp32)
__global__ __launch_bounds__(256) void k_gemm(const float* __restrict__ A,
                                              const _Float16* __restrict__ Wt_hi,
                                              const _Float16* __restrict__ Wt_lo,
                                              const float* __restrict__ scsh,
                                              float negmul,
                                              float* __restrict__ C) {
    __shared__ _Float16 sBH[16384];  // 32 KB
    __shared__ _Float16 sBL[16384];  // 32 KB
    const int tid = threadIdx.x;

    // cooperative fragment-ordered staging: 2048 granules x 16B each for hi and lo
#pragma unroll
    for (int it = 0; it < 8; ++it) {
        int g  = it * 256 + tid;
        int r  = g & 15;
        int kg = (g >> 4) & 3;
        int kc = (g >> 6) & 3;
        int n  = g >> 8;
        int glob = (n * 16 + r) * HH + kc * 32 + kg * 8;
        *reinterpret_cast<h8*>(&sBH[g * 8]) = *reinterpret_cast<const h8*>(Wt_hi + glob);
        *reinterpret_cast<h8*>(&sBL[g * 8]) = *reinterpret_cast<const h8*>(Wt_lo + glob);
    }
    __syncthreads();

    const int wave = tid >> 6;
    const int lane = tid & 63;
    const int r    = lane & 15;
    const int kg   = lane >> 4;        // 0..3
    const int row0 = blockIdx.x * 128 + wave * 32;

    f4 acc[2][8];
#pragma unroll
    for (int m = 0; m < 2; ++m)
#pragma unroll
        for (int n = 0; n < 8; ++n) acc[m][n] = (f4)0.0f;

    int ra0 = row0 + r;       if (ra0 >= NN) ra0 = NN - 1;
    int ra1 = row0 + 16 + r;  if (ra1 >= NN) ra1 = NN - 1;
    const float* A0 = A + (size_t)ra0 * HH + kg * 8;
    const float* A1 = A + (size_t)ra1 * HH + kg * 8;

#pragma unroll
    for (int kc = 0; kc < 4; ++kc) {
        const int k0 = kc * 32 + kg * 8;
        f4 scA = *reinterpret_cast<const f4*>(scsh + k0);
        f4 scB = *reinterpret_cast<const f4*>(scsh + k0 + 4);
        f4 shA = *reinterpret_cast<const f4*>(scsh + 128 + k0);
        f4 shB = *reinterpret_cast<const f4*>(scsh + 128 + k0 + 4);
        f4 a0x = *reinterpret_cast<const f4*>(A0 + kc * 32);
        f4 a0y = *reinterpret_cast<const f4*>(A0 + kc * 32 + 4);
        f4 a1x = *reinterpret_cast<const f4*>(A1 + kc * 32);
        f4 a1y = *reinterpret_cast<const f4*>(A1 + kc * 32 + 4);
        h8 a0hi, a0lo, a1hi, a1lo;
#pragma unroll
        for (int j = 0; j < 4; ++j) {
            float t;
            t = fmaf(a0x[j], scA[j], shA[j]); t = fmaxf(t, t * negmul);
            a0hi[j] = (_Float16)t;      a0lo[j] = (_Float16)(t - (float)a0hi[j]);
            t = fmaf(a0y[j], scB[j], shB[j]); t = fmaxf(t, t * negmul);
            a0hi[j + 4] = (_Float16)t;  a0lo[j + 4] = (_Float16)(t - (float)a0hi[j + 4]);
            t = fmaf(a1x[j], scA[j], shA[j]); t = fmaxf(t, t * negmul);
            a1hi[j] = (_Float16)t;      a1lo[j] = (_Float16)(t - (float)a1hi[j]);
            t = fmaf(a1y[j], scB[j], shB[j]); t = fmaxf(t, t * negmul);
            a1hi[j + 4] = (_Float16)t;  a1lo[j + 4] = (_Float16)(t - (float)a1hi[j + 4]);
        }
#pragma unroll
        for (int n = 0; n < 8; ++n) {
            int g = n * 256 + kc * 64 + lane;
            h8 bh = *reinterpret_cast<const h8*>(&sBH[g * 8]);
            h8 bl = *reinterpret_cast<const h8*>(&sBL[g * 8]);
            // D = W^T · X^T : A-operand = weight frag, B-operand = activation frag
            acc[0][n] = __builtin_amdgcn_mfma_f32_16x16x32_f16(bh, a0hi, acc[0][n], 0, 0, 0);
            acc[0][n] = __builtin_amdgcn_mfma_f32_16x16x32_f16(bl, a0hi, acc[0][n], 0, 0, 0);
            acc[0][n] = __builtin_amdgcn_mfma_f32_16x16x32_f16(bh, a0lo, acc[0][n], 0, 0, 0);
            acc[1][n] = __builtin_amdgcn_mfma_f32_16x16x32_f16(bh, a1hi, acc[1][n], 0, 0, 0);
            acc[1][n] = __builtin_amdgcn_mfma_f32_16x16x32_f16(bl, a1hi, acc[1][n], 0, 0, 0);
            acc[1][n] = __builtin_amdgcn_mfma_f32_16x16x32_f16(bh, a1lo, acc[1][n], 0, 0, 0);
        }
    }

    // D^T mapping: lane (r,kg) holds C[row0 + m*16 + r][n*16 + kg*4 + i], i=0..3 -> f4
#pragma unroll
    for (int m = 0; m < 2; ++m) {
        int rr = row0 + m * 16 + r;
        if (rr < NN) {
            float* Crow = C + (size_t)rr * HH + kg * 4;
#pragma unroll
            for (int n = 0; n < 8; ++n)
                *reinterpret_cast<f4*>(Crow + n * 16) = acc[m][n];
        }
    }
}

// ------- gather aggregation (fp32): one wave per node, 8-deep masked unroll -------
// 100K-wave TLP + 8 independent row loads in flight (mean degree ~6 => most nodes
// finish the edge loop in one iteration). OOB slots read cache-hot row 0 x norm 0.
__global__ __launch_bounds__(256) void k_gather(const float* __restrict__ h1,
                                                const int* __restrict__ offsets,
                                                const int* __restrict__ degi,
                                                const int2* __restrict__ csr,
                                                const float* __restrict__ dinv,
                                                float* __restrict__ h2) {
    int gid  = blockIdx.x * 256 + threadIdx.x;
    int node = gid >> 6;
    int lane = gid & 63;
    if (node >= NN) return;
    float di = dinv[node];
    f2 acc[8];
    acc[0] = reinterpret_cast<const f2*>(h1 + (size_t)node * HH)[lane] * (di * di);
#pragma unroll
    for (int j = 1; j < 8; ++j) acc[j] = (f2)0.0f;
    const int start = offsets[node];
    const int end   = start + degi[node];
    for (int b = start; b < end; b += 8) {
        int2 ce[8];
        ce[0] = csr[b];
#pragma unroll
        for (int j = 1; j < 8; ++j)
            ce[j] = (b + j < end) ? csr[b + j] : make_int2(0, 0);
        f2 v[8];
#pragma unroll
        for (int j = 0; j < 8; ++j)
            v[j] = reinterpret_cast<const f2*>(h1 + (size_t)ce[j].x * HH)[lane];
#pragma unroll
        for (int j = 0; j < 8; ++j)
            acc[j] += v[j] * __int_as_float(ce[j].y);
    }
#pragma unroll
    for (int j = 0; j < 4; ++j) acc[j] += acc[j + 4];
    acc[0] += acc[2];
    acc[1] += acc[3];
    acc[0] += acc[1];
    reinterpret_cast<f2*>(h2 + (size_t)node * HH)[lane] = acc[0];
}

// ------- BN stats phase 1: per-block partial sum/sumsq, NO atomics -------
__global__ __launch_bounds__(256) void k_bnstats(const float* __restrict__ h,
                                                 float* __restrict__ partial) {
    __shared__ f4 ls[8][32];
    __shared__ f4 lss[8][32];
    const int q  = threadIdx.x & 31;
    const int rg = threadIdx.x >> 5;
    const int r0 = blockIdx.x * 128;
    int rend = r0 + 128;
    if (rend > NN) rend = NN;
    f4 s = (f4)0.0f, ss = (f4)0.0f;
    for (int r = r0 + rg; r < rend; r += 8) {
        f4 v = *reinterpret_cast<const f4*>(h + (size_t)r * HH + q * 4);
        s += v;
        ss += v * v;
    }
    ls[rg][q] = s;
    lss[rg][q] = ss;
    __syncthreads();
    if (rg == 0) {
        f4 st = ls[0][q];
#pragma unroll
        for (int g = 1; g < 8; ++g) st += ls[g][q];
        *reinterpret_cast<f4*>(&partial[(size_t)blockIdx.x * 256 + q * 4]) = st;
    } else if (rg == 1) {
        f4 sq = lss[0][q];
#pragma unroll
        for (int g = 1; g < 8; ++g) sq += lss[g][q];
        *reinterpret_cast<f4*>(&partial[(size_t)blockIdx.x * 256 + 128 + q * 4]) = sq;
    }
}

// ------- BN stats phase 2a: 32 blocks each sum ~25 partial rows (coalesced) -------
__global__ void k_sred1(const float* __restrict__ partial, float* __restrict__ level2) {
    int c = threadIdx.x; // 256
    int b0 = blockIdx.x * RPB;
    int b1 = b0 + RPB;
    if (b1 > NBS) b1 = NBS;
    float s = 0.0f;
    for (int b = b0; b < b1; ++b) s += partial[(size_t)b * 256 + c];
    level2[(size_t)blockIdx.x * 256 + c] = s;
}

// ------- BN stats phase 2b: final sum over 32 level-2 rows -------
__global__ void k_sred2(const float* __restrict__ level2, float* __restrict__ stats) {
    int c = threadIdx.x; // 256
    float s = 0.0f;
#pragma unroll
    for (int b = 0; b < L2B; ++b) s += level2[(size_t)b * 256 + c];
    stats[c] = s;
}

// ------- final-layer BN apply + ReLU (prep fused): fp32 h2 -> fp16 x5 -------
__global__ void k_bnapply(const float* __restrict__ h2, const float* __restrict__ stats,
                          const float* __restrict__ gamma, const float* __restrict__ beta,
                          _Float16* __restrict__ xh) {
    int idx = blockIdx.x * 256 + threadIdx.x; // over NN*64 pairs
    if (idx >= NN * 64) return;
    int cp = idx & 63;
    int c0 = 2 * cp, c1 = c0 + 1;
    const float inv_n = 1.0f / (float)NN;
    float m0 = stats[c0] * inv_n, m1 = stats[c1] * inv_n;
    float v0s = stats[128 + c0] * inv_n - m0 * m0;
    float v1s = stats[128 + c1] * inv_n - m1 * m1;
    float sc0 = gamma[c0] * rsqrtf(v0s + BN_EPS);
    float sc1 = gamma[c1] * rsqrtf(v1s + BN_EPS);
    float sh0 = beta[c0] - m0 * sc0;
    float sh1 = beta[c1] - m1 * sc1;
    f2 v = reinterpret_cast<const f2*>(h2)[idx];
    float t0 = fmaf(v[0], sc0, sh0);
    float t1 = fmaf(v[1], sc1, sh1);
    t0 = fmaxf(t0, 0.0f);
    t1 = fmaxf(t1, 0.0f);
    h2x o;
    o[0] = (_Float16)t0;
    o[1] = (_Float16)t1;
    reinterpret_cast<h2x*>(xh)[idx] = o;
}

// ---------------- final: 16 lanes per edge, fp16 rows, fp32 math ----------------
__global__ __launch_bounds__(256) void k_final(const _Float16* __restrict__ x,
                                               const int* __restrict__ ei,
                                               const float* __restrict__ fcw,
                                               const float* __restrict__ fcb,
                                               float* __restrict__ out) {
    int gid  = blockIdx.x * 256 + threadIdx.x;
    int e    = gid >> 4;          // 16 lanes per edge
    int l16  = gid & 15;
    if (e >= NE) return;
    int a = ei[e];
    int b = ei[NE + e];
    h8 va = *reinterpret_cast<const h8*>(x + (size_t)a * HH + l16 * 8);
    h8 vb = *reinterpret_cast<const h8*>(x + (size_t)b * HH + l16 * 8);
    f4 w0 = *reinterpret_cast<const f4*>(fcw + l16 * 8);
    f4 w1 = *reinterpret_cast<const f4*>(fcw + l16 * 8 + 4);
    float p = 0.0f;
#pragma unroll
    for (int j = 0; j < 4; ++j) {
        p += (float)va[j] * (float)vb[j] * w0[j];
        p += (float)va[j + 4] * (float)vb[j + 4] * w1[j];
    }
#pragma unroll
    for (int off = 8; off > 0; off >>= 1) p += __shfl_xor(p, off, 64);
    if (l16 == 0) out[e] = 1.0f / (1.0f + expf(-(p + fcb[0])));
}

extern "C" void kernel_launch(void* const* d_in, const int* in_sizes, int n_in,
                              void* d_out, int out_size, void* d_ws, size_t ws_size,
                              hipStream_t stream) {
    const float* x   = (const float*)d_in[0];
    const void*  ei_raw = d_in[1];
    const float* cw  = (const float*)d_in[2];
    // d_in[3] = conv_b: cancels exactly through BatchNorm -> unused
    const float* gam = (const float*)d_in[4];
    const float* bet = (const float*)d_in[5];
    const float* fcw = (const float*)d_in[6];
    const float* fcb = (const float*)d_in[7];
    float* out = (float*)d_out;

    const size_t NH = (size_t)NN * HH;
    unsigned char* p = (unsigned char*)d_ws;
    float* h1 = (float*)p;       p += NH * 4;            // fp32 gemm out
    float* h2 = (float*)p;       p += NH * 4;            // fp32 aggregated
    _Float16* xh = (_Float16*)p; p += NH * 2;            // fp16 x5 for edge head
    _Float16* WtH = (_Float16*)p; p += (size_t)NL * HH * HH * 2;
    _Float16* WtL = (_Float16*)p; p += (size_t)NL * HH * HH * 2;
    int2*  csr   = (int2*)p;     p += (size_t)NE * 8;
    float* dinv  = (float*)p;    p += NN * 4;
    float* stats = (float*)p;    p += NL * 256 * 4;
    float* scsh  = (float*)p;    p += NL * 256 * 4;
    float* partial = (float*)p;  p += (size_t)NBS * 256 * 4;
    float* level2  = (float*)p;  p += (size_t)L2B * 256 * 4;
    int*   ei    = (int*)p;      p += (size_t)2 * NE * 4;
    int*   degi  = (int*)p;      p += NN * 4;
    int*   incl  = (int*)p;      p += NN * 4;
    int*   offsets = (int*)p;    p += NN * 4;
    int*   cursor  = (int*)p;    p += NN * 4;
    int*   blocksums = (int*)p;  p += NB * 4;
    int*   blockoffs = (int*)p;  p += NB * 4;
    int*   flag  = (int*)p;

    // normalize edge index dtype to int32
    k_probe<<<1, 64, 0, stream>>>((const unsigned long long*)ei_raw, flag);
    k_convert<<<(2 * NE + 255) / 256, 256, 0, stream>>>(ei_raw, flag, ei);

    // degrees -> dinv; CSR build
    k_zero<<<(NN + 255) / 256, 256, 0, stream>>>(degi, NN);
    k_count_deg<<<(NE + 255) / 256, 256, 0, stream>>>(ei + NE, degi);
    k_dinv<<<(NN + 255) / 256, 256, 0, stream>>>(degi, dinv);
    k_scan1<<<NB, 256, 0, stream>>>(degi, incl, blocksums);
    k_scan2<<<1, 512, 0, stream>>>(blocksums, blockoffs);
    k_scan3<<<NB, 256, 0, stream>>>(incl, degi, blockoffs, offsets, cursor);
    k_scatter<<<(NE + 255) / 256, 256, 0, stream>>>(ei, dinv, offsets, cursor, csr);

    // split weights (fp16 hi/lo, transposed)
    k_wt<<<(NL * HH * HH + 255) / 256, 256, 0, stream>>>(cw, WtH, WtL);

    for (int l = 0; l < NL; ++l) {
        k_prep<<<1, 128, 0, stream>>>(
            (l == 0) ? stats : stats + (size_t)(l - 1) * 256,
            (l == 0) ? gam : gam + (size_t)(l - 1) * HH,
            (l == 0) ? bet : bet + (size_t)(l - 1) * HH,
            (l == 0) ? 0 : 1, scsh + (size_t)l * 256);
        k_gemm<<<(NN + 127) / 128, 256, 0, stream>>>(
            (l == 0) ? x : h2, WtH + (size_t)l * HH * HH, WtL + (size_t)l * HH * HH,
            scsh + (size_t)l * 256, (l == 0) ? 1.0f : 0.0f, h1);
        k_gather<<<(NN * 64 + 255) / 256, 256, 0, stream>>>(h1, offsets, degi, csr, dinv, h2);
        k_bnstats<<<NBS, 256, 0, stream>>>(h2, partial);
        k_sred1<<<L2B, 256, 0, stream>>>(partial, level2);
        k_sred2<<<1, 256, 0, stream>>>(level2, stats + (size_t)l * 256);
    }
    // materialize x5 (fp16) for the edge head (BN prep fused)
    k_bnapply<<<(NN * 64 + 255) / 256, 256, 0, stream>>>(h2, stats + (size_t)(NL - 1) * 256,
                                                         gam + (size_t)(NL - 1) * HH,
                                                         bet + (size_t)(NL - 1) * HH, xh);
    k_final<<<(NE * 16 + 255) / 256, 256, 0, stream>>>(xh, ei, fcw, fcb, out);
}

// Round 13
// 690.791 us; speedup vs baseline: 1.7707x; 1.0617x over previous
//
#include <hip/hip_runtime.h>

#define NN 100000
#define NE 600000
#define HH 128
#define NL 5
#define BN_EPS 1e-5f
#define NB 391   // (NN+255)/256
#define NBS 782  // (NN+127)/128  bnstats blocks
#define L2B 32   // level-2 reduce blocks
#define RPB 25   // ceil(NBS/L2B) rows per level-2 block

typedef float f4 __attribute__((ext_vector_type(4)));
typedef float f2 __attribute__((ext_vector_type(2)));
typedef _Float16 h8 __attribute__((ext_vector_type(8)));
typedef _Float16 h2x __attribute__((ext_vector_type(2)));

// ---------------- edge-index dtype probe + normalize to int32 ----------------
__global__ void k_probe(const unsigned long long* __restrict__ e, int* __restrict__ flag) {
    if (blockIdx.x == 0 && threadIdx.x == 0) {
        int ok = 1;
        for (int i = 0; i < 64; ++i)
            if (e[i] >= (unsigned long long)NN) ok = 0;
        *flag = ok; // 1 => int64, 0 => int32
    }
}

__global__ void k_convert(const void* __restrict__ src, const int* __restrict__ flag,
                          int* __restrict__ dst) {
    int i = blockIdx.x * 256 + threadIdx.x;
    if (i >= 2 * NE) return;
    if (*flag) dst[i] = (int)((const long long*)src)[i];
    else       dst[i] = ((const int*)src)[i];
}

__global__ void k_zero(int* __restrict__ p, int n) {
    int i = blockIdx.x * 256 + threadIdx.x;
    if (i < n) p[i] = 0;
}

// ---------------- degree / dinv ----------------
__global__ void k_count_deg(const int* __restrict__ col, int* __restrict__ degi) {
    int e = blockIdx.x * 256 + threadIdx.x;
    if (e < NE) atomicAdd(&degi[col[e]], 1);
}

__global__ void k_dinv(const int* __restrict__ degi, float* __restrict__ dinv) {
    int i = blockIdx.x * 256 + threadIdx.x;
    if (i < NN) dinv[i] = rsqrtf((float)degi[i] + 1.0f);
}

// ---------------- prefix scan ----------------
__global__ __launch_bounds__(256) void k_scan1(const int* __restrict__ degi,
                                               int* __restrict__ incl,
                                               int* __restrict__ blocksums) {
    __shared__ int sd[256];
    int tid = threadIdx.x;
    int i = blockIdx.x * 256 + tid;
    int v = (i < NN) ? degi[i] : 0;
    sd[tid] = v;
    __syncthreads();
#pragma unroll
    for (int off = 1; off < 256; off <<= 1) {
        int t = (tid >= off) ? sd[tid - off] : 0;
        __syncthreads();
        sd[tid] += t;
        __syncthreads();
    }
    if (i < NN) incl[i] = sd[tid];
    if (tid == 255) blocksums[blockIdx.x] = sd[255];
}

__global__ __launch_bounds__(512) void k_scan2(const int* __restrict__ blocksums,
                                               int* __restrict__ blockoffs) {
    __shared__ int sd[512];
    int tid = threadIdx.x;
    int v = (tid < NB) ? blocksums[tid] : 0;
    sd[tid] = v;
    __syncthreads();
#pragma unroll
    for (int off = 1; off < 512; off <<= 1) {
        int t = (tid >= off) ? sd[tid - off] : 0;
        __syncthreads();
        sd[tid] += t;
        __syncthreads();
    }
    if (tid < NB) blockoffs[tid] = sd[tid] - v;
}

__global__ void k_scan3(const int* __restrict__ incl, const int* __restrict__ degi,
                        const int* __restrict__ blockoffs,
                        int* __restrict__ offsets, int* __restrict__ cursor) {
    int i = blockIdx.x * 256 + threadIdx.x;
    if (i >= NN) return;
    offsets[i] = incl[i] - degi[i] + blockoffs[blockIdx.x];
    cursor[i] = 0;
}

__global__ void k_scatter(const int* __restrict__ ei, const float* __restrict__ dinv,
                          const int* __restrict__ offsets, int* __restrict__ cursor,
                          int2* __restrict__ csr) {
    int e = blockIdx.x * 256 + threadIdx.x;
    if (e >= NE) return;
    int r = ei[e], c = ei[NE + e];
    int pos = offsets[c] + atomicAdd(&cursor[c], 1);
    int2 v;
    v.x = r;
    v.y = __float_as_int(dinv[r] * dinv[c]);
    csr[pos] = v;
}

// ---- transpose + split-cast weights: Wt{hi,lo}[l][n][k] from W[l][k][n] (fp32) ----
__global__ void k_wt(const float* __restrict__ W, _Float16* __restrict__ Wt_hi,
                     _Float16* __restrict__ Wt_lo) {
    int gid = blockIdx.x * 256 + threadIdx.x; // over NL*128*128
    if (gid >= NL * HH * HH) return;
    int l = gid >> 14;
    int rem = gid & 16383;
    int n = rem >> 7;
    int k = rem & 127;
    float w = W[l * HH * HH + k * HH + n];
    _Float16 hi = (_Float16)w;
    _Float16 lo = (_Float16)(w - (float)hi);
    Wt_hi[gid] = hi;
    Wt_lo[gid] = lo;
}

// ---- per-layer BN scale/shift: sc = gamma*rsqrt(var+eps), sh = beta-mean*sc ----
__global__ void k_prep(const float* __restrict__ stats, const float* __restrict__ gamma,
                       const float* __restrict__ beta, int mode, float* __restrict__ scsh) {
    int k = threadIdx.x; // 128 threads
    float sc = 1.0f, sh = 0.0f;
    if (mode) {
        const float inv_n = 1.0f / (float)NN;
        float mean = stats[k] * inv_n;
        float var  = stats[128 + k] * inv_n - mean * mean;
        sc = gamma[k] * rsqrtf(var + BN_EPS);
        sh = beta[k] - mean * sc;
    }
    scsh[k] = sc;
    scsh[128 + k] = sh;
}

// ---------------- fused GEMM: h1 = relu?(bn(A)) @ W, split-fp16 MFMA, fp32 I/O ------
// 256-row tile/block (391 blocks = single dispatch round at 2 blocks/CU with 64KB LDS).
// Wave computes 64 rows x 128 cols. B staged once per block in fragment order.
// Swapped-operand MFMA: D = W^T·X^T = C^T => f4 C-stores.
// h1 = Xhi@Whi + Xhi@Wlo + Xlo@Whi  (error ~2^-22 rel; effectively fp32)
__global__ __launch_bounds__(256) void k_gemm(const float* __restrict__ A,
                                              const _Float16* __restrict__ Wt_hi,
                                              const _Float16* __restrict__ Wt_lo,
                                              const float* __restrict__ scsh,
                                              float negmul,
                                              float* __restrict__ C) {
    __shared__ _Float16 sBH[16384];  // 32 KB
    __shared__ _Float16 sBL[16384];  // 32 KB
    const int tid = threadIdx.x;

    // cooperative fragment-ordered staging: 2048 granules x 16B each for hi and lo
#pragma unroll
    for (int it = 0; it < 8; ++it) {
        int g  = it * 256 + tid;
        int rr = g & 15;
        int kg = (g >> 4) & 3;
        int kc = (g >> 6) & 3;
        int n  = g >> 8;
        int glob = (n * 16 + rr) * HH + kc * 32 + kg * 8;
        *reinterpret_cast<h8*>(&sBH[g * 8]) = *reinterpret_cast<const h8*>(Wt_hi + glob);
        *reinterpret_cast<h8*>(&sBL[g * 8]) = *reinterpret_cast<const h8*>(Wt_lo + glob);
    }
    __syncthreads();

    const int wave = tid >> 6;
    const int lane = tid & 63;
    const int r    = lane & 15;
    const int kg   = lane >> 4;        // 0..3
    const int row0 = blockIdx.x * 256 + wave * 64;

    f4 acc[4][8];
#pragma unroll
    for (int m = 0; m < 4; ++m)
#pragma unroll
        for (int n = 0; n < 8; ++n) acc[m][n] = (f4)0.0f;

    const float* Ap[4];
#pragma unroll
    for (int m = 0; m < 4; ++m) {
        int ra = row0 + m * 16 + r;
        if (ra >= NN) ra = NN - 1;
        Ap[m] = A + (size_t)ra * HH + kg * 8;
    }

#pragma unroll
    for (int kc = 0; kc < 4; ++kc) {
        const int k0 = kc * 32 + kg * 8;
        f4 scA = *reinterpret_cast<const f4*>(scsh + k0);
        f4 scB = *reinterpret_cast<const f4*>(scsh + k0 + 4);
        f4 shA = *reinterpret_cast<const f4*>(scsh + 128 + k0);
        f4 shB = *reinterpret_cast<const f4*>(scsh + 128 + k0 + 4);
        h8 ahi[4], alo[4];
#pragma unroll
        for (int m = 0; m < 4; ++m) {
            f4 ax = *reinterpret_cast<const f4*>(Ap[m] + kc * 32);
            f4 ay = *reinterpret_cast<const f4*>(Ap[m] + kc * 32 + 4);
#pragma unroll
            for (int j = 0; j < 4; ++j) {
                float t;
                t = fmaf(ax[j], scA[j], shA[j]); t = fmaxf(t, t * negmul);
                ahi[m][j] = (_Float16)t;      alo[m][j] = (_Float16)(t - (float)ahi[m][j]);
                t = fmaf(ay[j], scB[j], shB[j]); t = fmaxf(t, t * negmul);
                ahi[m][j + 4] = (_Float16)t;  alo[m][j + 4] = (_Float16)(t - (float)ahi[m][j + 4]);
            }
        }
#pragma unroll
        for (int n = 0; n < 8; ++n) {
            int g = n * 256 + kc * 64 + lane;
            h8 bh = *reinterpret_cast<const h8*>(&sBH[g * 8]);
            h8 bl = *reinterpret_cast<const h8*>(&sBL[g * 8]);
            // D = W^T · X^T : A-operand = weight frag, B-operand = activation frag
#pragma unroll
            for (int m = 0; m < 4; ++m) {
                acc[m][n] = __builtin_amdgcn_mfma_f32_16x16x32_f16(bh, ahi[m], acc[m][n], 0, 0, 0);
                acc[m][n] = __builtin_amdgcn_mfma_f32_16x16x32_f16(bl, ahi[m], acc[m][n], 0, 0, 0);
                acc[m][n] = __builtin_amdgcn_mfma_f32_16x16x32_f16(bh, alo[m], acc[m][n], 0, 0, 0);
            }
        }
    }

    // D^T mapping: lane (r,kg) holds C[row0 + m*16 + r][n*16 + kg*4 + i], i=0..3 -> f4
#pragma unroll
    for (int m = 0; m < 4; ++m) {
        int rr = row0 + m * 16 + r;
        if (rr < NN) {
            float* Crow = C + (size_t)rr * HH + kg * 4;
#pragma unroll
            for (int n = 0; n < 8; ++n)
                *reinterpret_cast<f4*>(Crow + n * 16) = acc[m][n];
        }
    }
}

// ------- gather aggregation (fp32): one wave per node, 4-deep masked unroll -------
// Round-11 proven config: 100K-wave TLP, 4 independent row loads in flight,
// VGPR 24 / occupancy ~66%. OOB slots read cache-hot row 0 x norm 0.
__global__ __launch_bounds__(256) void k_gather(const float* __restrict__ h1,
                                                const int* __restrict__ offsets,
                                                const int* __restrict__ degi,
                                                const int2* __restrict__ csr,
                                                const float* __restrict__ dinv,
                                                float* __restrict__ h2) {
    int gid  = blockIdx.x * 256 + threadIdx.x;
    int node = gid >> 6;
    int lane = gid & 63;
    if (node >= NN) return;
    float di = dinv[node];
    f2 acc0 = reinterpret_cast<const f2*>(h1 + (size_t)node * HH)[lane] * (di * di);
    f2 acc1 = (f2)0.0f, acc2 = (f2)0.0f, acc3 = (f2)0.0f;
    const int start = offsets[node];
    const int end   = start + degi[node];
    for (int b = start; b < end; b += 4) {
        int2 ce0 = csr[b];
        int2 ce1 = (b + 1 < end) ? csr[b + 1] : make_int2(0, 0);
        int2 ce2 = (b + 2 < end) ? csr[b + 2] : make_int2(0, 0);
        int2 ce3 = (b + 3 < end) ? csr[b + 3] : make_int2(0, 0);
        f2 v0 = reinterpret_cast<const f2*>(h1 + (size_t)ce0.x * HH)[lane];
        f2 v1 = reinterpret_cast<const f2*>(h1 + (size_t)ce1.x * HH)[lane];
        f2 v2 = reinterpret_cast<const f2*>(h1 + (size_t)ce2.x * HH)[lane];
        f2 v3 = reinterpret_cast<const f2*>(h1 + (size_t)ce3.x * HH)[lane];
        acc0 += v0 * __int_as_float(ce0.y);
        acc1 += v1 * __int_as_float(ce1.y);
        acc2 += v2 * __int_as_float(ce2.y);
        acc3 += v3 * __int_as_float(ce3.y);
    }
    acc0 += acc2;
    acc1 += acc3;
    acc0 += acc1;
    reinterpret_cast<f2*>(h2 + (size_t)node * HH)[lane] = acc0;
}

// ------- BN stats phase 1: per-block partial sum/sumsq, NO atomics -------
__global__ __launch_bounds__(256) void k_bnstats(const float* __restrict__ h,
                                                 float* __restrict__ partial) {
    __shared__ f4 ls[8][32];
    __shared__ f4 lss[8][32];
    const int q  = threadIdx.x & 31;
    const int rg = threadIdx.x >> 5;
    const int r0 = blockIdx.x * 128;
    int rend = r0 + 128;
    if (rend > NN) rend = NN;
    f4 s = (f4)0.0f, ss = (f4)0.0f;
    for (int r = r0 + rg; r < rend; r += 8) {
        f4 v = *reinterpret_cast<const f4*>(h + (size_t)r * HH + q * 4);
        s += v;
        ss += v * v;
    }
    ls[rg][q] = s;
    lss[rg][q] = ss;
    __syncthreads();
    if (rg == 0) {
        f4 st = ls[0][q];
#pragma unroll
        for (int g = 1; g < 8; ++g) st += ls[g][q];
        *reinterpret_cast<f4*>(&partial[(size_t)blockIdx.x * 256 + q * 4]) = st;
    } else if (rg == 1) {
        f4 sq = lss[0][q];
#pragma unroll
        for (int g = 1; g < 8; ++g) sq += lss[g][q];
        *reinterpret_cast<f4*>(&partial[(size_t)blockIdx.x * 256 + 128 + q * 4]) = sq;
    }
}

// ------- BN stats phase 2a: 32 blocks each sum ~25 partial rows (coalesced) -------
__global__ void k_sred1(const float* __restrict__ partial, float* __restrict__ level2) {
    int c = threadIdx.x; // 256
    int b0 = blockIdx.x * RPB;
    int b1 = b0 + RPB;
    if (b1 > NBS) b1 = NBS;
    float s = 0.0f;
    for (int b = b0; b < b1; ++b) s += partial[(size_t)b * 256 + c];
    level2[(size_t)blockIdx.x * 256 + c] = s;
}

// ------- BN stats phase 2b: final sum over 32 level-2 rows -------
__global__ void k_sred2(const float* __restrict__ level2, float* __restrict__ stats) {
    int c = threadIdx.x; // 256
    float s = 0.0f;
#pragma unroll
    for (int b = 0; b < L2B; ++b) s += level2[(size_t)b * 256 + c];
    stats[c] = s;
}

// ------- final-layer BN apply + ReLU (prep fused): fp32 h2 -> fp16 x5 -------
__global__ void k_bnapply(const float* __restrict__ h2, const float* __restrict__ stats,
                          const float* __restrict__ gamma, const float* __restrict__ beta,
                          _Float16* __restrict__ xh) {
    int idx = blockIdx.x * 256 + threadIdx.x; // over NN*64 pairs
    if (idx >= NN * 64) return;
    int cp = idx & 63;
    int c0 = 2 * cp, c1 = c0 + 1;
    const float inv_n = 1.0f / (float)NN;
    float m0 = stats[c0] * inv_n, m1 = stats[c1] * inv_n;
    float v0s = stats[128 + c0] * inv_n - m0 * m0;
    float v1s = stats[128 + c1] * inv_n - m1 * m1;
    float sc0 = gamma[c0] * rsqrtf(v0s + BN_EPS);
    float sc1 = gamma[c1] * rsqrtf(v1s + BN_EPS);
    float sh0 = beta[c0] - m0 * sc0;
    float sh1 = beta[c1] - m1 * sc1;
    f2 v = reinterpret_cast<const f2*>(h2)[idx];
    float t0 = fmaf(v[0], sc0, sh0);
    float t1 = fmaf(v[1], sc1, sh1);
    t0 = fmaxf(t0, 0.0f);
    t1 = fmaxf(t1, 0.0f);
    h2x o;
    o[0] = (_Float16)t0;
    o[1] = (_Float16)t1;
    reinterpret_cast<h2x*>(xh)[idx] = o;
}

// ---------------- final: 16 lanes per edge, fp16 rows, fp32 math ----------------
__global__ __launch_bounds__(256) void k_final(const _Float16* __restrict__ x,
                                               const int* __restrict__ ei,
                                               const float* __restrict__ fcw,
                                               const float* __restrict__ fcb,
                                               float* __restrict__ out) {
    int gid  = blockIdx.x * 256 + threadIdx.x;
    int e    = gid >> 4;          // 16 lanes per edge
    int l16  = gid & 15;
    if (e >= NE) return;
    int a = ei[e];
    int b = ei[NE + e];
    h8 va = *reinterpret_cast<const h8*>(x + (size_t)a * HH + l16 * 8);
    h8 vb = *reinterpret_cast<const h8*>(x + (size_t)b * HH + l16 * 8);
    f4 w0 = *reinterpret_cast<const f4*>(fcw + l16 * 8);
    f4 w1 = *reinterpret_cast<const f4*>(fcw + l16 * 8 + 4);
    float p = 0.0f;
#pragma unroll
    for (int j = 0; j < 4; ++j) {
        p += (float)va[j] * (float)vb[j] * w0[j];
        p += (float)va[j + 4] * (float)vb[j + 4] * w1[j];
    }
#pragma unroll
    for (int off = 8; off > 0; off >>= 1) p += __shfl_xor(p, off, 64);
    if (l16 == 0) out[e] = 1.0f / (1.0f + expf(-(p + fcb[0])));
}

extern "C" void kernel_launch(void* const* d_in, const int* in_sizes, int n_in,
                              void* d_out, int out_size, void* d_ws, size_t ws_size,
                              hipStream_t stream) {
    const float* x   = (const float*)d_in[0];
    const void*  ei_raw = d_in[1];
    const float* cw  = (const float*)d_in[2];
    // d_in[3] = conv_b: cancels exactly through BatchNorm -> unused
    const float* gam = (const float*)d_in[4];
    const float* bet = (const float*)d_in[5];
    const float* fcw = (const float*)d_in[6];
    const float* fcb = (const float*)d_in[7];
    float* out = (float*)d_out;

    const size_t NH = (size_t)NN * HH;
    unsigned char* p = (unsigned char*)d_ws;
    float* h1 = (float*)p;       p += NH * 4;            // fp32 gemm out
    float* h2 = (float*)p;       p += NH * 4;            // fp32 aggregated
    _Float16* xh = (_Float16*)p; p += NH * 2;            // fp16 x5 for edge head
    _Float16* WtH = (_Float16*)p; p += (size_t)NL * HH * HH * 2;
    _Float16* WtL = (_Float16*)p; p += (size_t)NL * HH * HH * 2;
    int2*  csr   = (int2*)p;     p += (size_t)NE * 8;
    float* dinv  = (float*)p;    p += NN * 4;
    float* stats = (float*)p;    p += NL * 256 * 4;
    float* scsh  = (float*)p;    p += NL * 256 * 4;
    float* partial = (float*)p;  p += (size_t)NBS * 256 * 4;
    float* level2  = (float*)p;  p += (size_t)L2B * 256 * 4;
    int*   ei    = (int*)p;      p += (size_t)2 * NE * 4;
    int*   degi  = (int*)p;      p += NN * 4;
    int*   incl  = (int*)p;      p += NN * 4;
    int*   offsets = (int*)p;    p += NN * 4;
    int*   cursor  = (int*)p;    p += NN * 4;
    int*   blocksums = (int*)p;  p += NB * 4;
    int*   blockoffs = (int*)p;  p += NB * 4;
    int*   flag  = (int*)p;

    // normalize edge index dtype to int32
    k_probe<<<1, 64, 0, stream>>>((const unsigned long long*)ei_raw, flag);
    k_convert<<<(2 * NE + 255) / 256, 256, 0, stream>>>(ei_raw, flag, ei);

    // degrees -> dinv; CSR build
    k_zero<<<(NN + 255) / 256, 256, 0, stream>>>(degi, NN);
    k_count_deg<<<(NE + 255) / 256, 256, 0, stream>>>(ei + NE, degi);
    k_dinv<<<(NN + 255) / 256, 256, 0, stream>>>(degi, dinv);
    k_scan1<<<NB, 256, 0, stream>>>(degi, incl, blocksums);
    k_scan2<<<1, 512, 0, stream>>>(blocksums, blockoffs);
    k_scan3<<<NB, 256, 0, stream>>>(incl, degi, blockoffs, offsets, cursor);
    k_scatter<<<(NE + 255) / 256, 256, 0, stream>>>(ei, dinv, offsets, cursor, csr);

    // split weights (fp16 hi/lo, transposed)
    k_wt<<<(NL * HH * HH + 255) / 256, 256, 0, stream>>>(cw, WtH, WtL);

    for (int l = 0; l < NL; ++l) {
        k_prep<<<1, 128, 0, stream>>>(
            (l == 0) ? stats : stats + (size_t)(l - 1) * 256,
            (l == 0) ? gam : gam + (size_t)(l - 1) * HH,
            (l == 0) ? bet : bet + (size_t)(l - 1) * HH,
            (l == 0) ? 0 : 1, scsh + (size_t)l * 256);
        k_gemm<<<(NN + 255) / 256, 256, 0, stream>>>(
            (l == 0) ? x : h2, WtH + (size_t)l * HH * HH, WtL + (size_t)l * HH * HH,
            scsh + (size_t)l * 256, (l == 0) ? 1.0f : 0.0f, h1);
        k_gather<<<(NN * 64 + 255) / 256, 256, 0, stream>>>(h1, offsets, degi, csr, dinv, h2);
        k_bnstats<<<NBS, 256, 0, stream>>>(h2, partial);
        k_sred1<<<L2B, 256, 0, stream>>>(partial, level2);
        k_sred2<<<1, 256, 0, stream>>>(level2, stats + (size_t)l * 256);
    }
    // materialize x5 (fp16) for the edge head (BN prep fused)
    k_bnapply<<<(NN * 64 + 255) / 256, 256, 0, stream>>>(h2, stats + (size_t)(NL - 1) * 256,
                                                         gam + (size_t)(NL - 1) * HH,
                                                         bet + (size_t)(NL - 1) * HH, xh);
    k_final<<<(NE * 16 + 255) / 256, 256, 0, stream>>>(xh, ei, fcw, fcb, out);
}